// Round 7
// baseline (406.293 us; speedup 1.0000x reference)
//
#include <hip/hip_runtime.h>
#include <cstdint>

typedef __bf16 bf16_t;
typedef bf16_t bf16x8 __attribute__((ext_vector_type(8)));
typedef float floatx4 __attribute__((ext_vector_type(4)));
typedef unsigned short ushort4v __attribute__((ext_vector_type(4)));

constexpr int N_NODES = 50000;
constexpr int N_EDGES = 800000;
constexpr int HID = 128;
constexpr int EH = 64;
constexpr int NCH = (N_NODES + 255) / 256;  // 196 buckets
constexpr int BKT_CAP = 4096;               // slots per bucket (mean ~2048)

__device__ __forceinline__ float silu_f(float x) {
    return x * __builtin_amdgcn_rcpf(1.0f + __expf(-x));
}

// ---------------------------------------------------------------------------
// Fused weight pack: all 6 weight tensors -> bf16 MFMA B-fragment order.
// Extra region at pk+262144: ew1 repacked as a fused [128 x 128] B so that
// P[n] = [ h@W1_top | h@W1_bot ] comes out of ONE K=128 GEMM per node.
// ---------------------------------------------------------------------------
__global__ __launch_bounds__(256) void pack_all_kernel(
    const float* __restrict__ embin, const float* __restrict__ embout,
    const float* __restrict__ ew1, const float* __restrict__ ew2,
    const float* __restrict__ nw1, const float* __restrict__ nw2,
    bf16_t* __restrict__ pk)
{
    int t = blockIdx.x * 256 + threadIdx.x;
    if (t >= 32768) {
        t -= 32768;
        int lane = t & 63, chunk = t >> 6;
        int ks = chunk & 3, nt = (chunk >> 2) & 7, l = chunk >> 5;
        int quad = lane >> 4, coln = lane & 15;
        const float* Wl = ew1 + l * 256 * 64;
        int kb = (nt >= 4 ? 128 : 0) + ks * 32 + quad * 8;
        int nc = (nt & 3) * 16 + coln;
        bf16x8 v;
#pragma unroll
        for (int j = 0; j < 8; j++) v[j] = (bf16_t)Wl[(kb + j) * 64 + nc];
        *(bf16x8*)(pk + 262144 + t * 8) = v;
        return;
    }
    const float* W; int K, Nc; int base; bf16_t* out;
    if (t < 1024)       { W = embin;  K = 64;  Nc = 128; base = 0;     out = pk; }
    else if (t < 2048)  { W = embout; K = 128; Nc = 64;  base = 1024;  out = pk + 8192; }
    else if (t < 10240) { W = ew1;    K = 256; Nc = 64;  base = 2048;  out = pk + 16384; }
    else if (t < 12288) { W = ew2;    K = 64;  Nc = 64;  base = 10240; out = pk + 81920; }
    else if (t < 24576) { W = nw1;    K = 192; Nc = 128; base = 12288; out = pk + 98304; }
    else                { W = nw2;    K = 128; Nc = 128; base = 24576; out = pk + 196608; }
    t -= base;
    int KS = K >> 5, NT = Nc >> 4;
    int lane = t & 63;
    int chunk = t >> 6;
    int ks = chunk % KS;
    int nt = (chunk / KS) % NT;
    int l  = chunk / (KS * NT);
    int quad = lane >> 4, coln = lane & 15;
    const float* Wl = W + l * K * Nc;
    bf16x8 v;
#pragma unroll
    for (int j = 0; j < 8; j++)
        v[j] = (bf16_t)Wl[(ks * 32 + quad * 8 + j) * Nc + nt * 16 + coln];
    *(bf16x8*)(out + t * 8) = v;
}

// ---------------------------------------------------------------------------
// SORT pass 1: bucketize masked edges by dst>>8 into fixed 4096-slot bucket
// regions. Per block: LDS histogram -> ONE global atomic per bucket (range
// reserve) -> LDS-cursor append of packed (r&255)<<16 | c.
// ---------------------------------------------------------------------------
__global__ __launch_bounds__(256) void bucketize_kernel(
    const int* __restrict__ ea, const int* __restrict__ eb,
    const int* __restrict__ ma, const int* __restrict__ mb,
    int* __restrict__ gcur, int* __restrict__ gbuf)
{
    int g = blockIdx.y;
    const int* e    = g ? eb : ea;
    const int* mask = g ? mb : ma;
    int* cur = gcur + g * 256;
    int* buf = gbuf + g * 256 * BKT_CAP;
    __shared__ int cnt[256];
    int t = threadIdx.x;
    cnt[t] = 0;
    __syncthreads();
    int base = blockIdx.x * 2048;
    int r[8], c[8]; bool v[8];
#pragma unroll
    for (int k = 0; k < 8; k++) {
        int i = base + k * 256 + t;
        bool ok = i < N_EDGES;
        int ii = ok ? i : 0;
        int rr = e[ii];
        int cc = e[N_EDGES + ii];
        v[k] = ok && (mask[rr] != 0);
        r[k] = rr; c[k] = cc;
        if (v[k]) atomicAdd(&cnt[rr >> 8], 1);
    }
    __syncthreads();
    int lc = cnt[t];
    int gb = 0;
    if (lc > 0) gb = atomicAdd(&cur[t], lc);  // reserve contiguous range
    cnt[t] = gb;                              // own slot only; safe pre-sync
    __syncthreads();
#pragma unroll
    for (int k = 0; k < 8; k++) {
        if (v[k]) {
            int bkt = r[k] >> 8;
            int p = atomicAdd(&cnt[bkt], 1);  // LDS cursor
            if (p < BKT_CAP)
                buf[bkt * BKT_CAP + p] = ((r[k] & 255) << 16) | c[k];
        }
    }
}

// ---------------------------------------------------------------------------
// SORT tiny scan: exclusive scan of 196 bucket counts per graph -> bases + M.
// ---------------------------------------------------------------------------
__global__ __launch_bounds__(256) void bucket_scan_kernel(
    const int* __restrict__ gcur, int* __restrict__ bases,
    int* __restrict__ mcnt_a, int* __restrict__ mcnt_b)
{
    int g = blockIdx.x;
    const int* cur = gcur + g * 256;
    int t = threadIdx.x, lane = t & 63, wv = t >> 6;
    int v = (t < NCH) ? min(cur[t], BKT_CAP) : 0;
    int s = v;
#pragma unroll
    for (int off = 1; off < 64; off <<= 1) {
        int u = __shfl_up(s, off, 64);
        if (lane >= off) s += u;
    }
    __shared__ int wsum[4];
    if (lane == 63) wsum[wv] = s;
    __syncthreads();
    int woff = 0;
    for (int w = 0; w < wv; w++) woff += wsum[w];
    int excl = s - v + woff;
    bases[g * 256 + t] = excl;
    if (t == NCH - 1) *(g ? mcnt_b : mcnt_a) = excl + v;
}

// ---------------------------------------------------------------------------
// SORT pass 2: per-bucket counting sort fully in LDS. ZERO global atomics.
// ---------------------------------------------------------------------------
__global__ __launch_bounds__(256) void bucket_sort_kernel(
    const int* __restrict__ gcur, const int* __restrict__ gbuf,
    const int* __restrict__ bases,
    int* __restrict__ ssrc_a, int* __restrict__ sdst_a,
    int* __restrict__ ssrc_b, int* __restrict__ sdst_b)
{
    int g = blockIdx.y, b = blockIdx.x;
    const int* buf = gbuf + g * 256 * BKT_CAP + b * BKT_CAP;
    int* ssrc = g ? ssrc_b : ssrc_a;
    int* sdst = g ? sdst_b : sdst_a;
    int cnt_e = min(gcur[g * 256 + b], BKT_CAP);
    int base = bases[g * 256 + b];
    __shared__ int h[256];
    __shared__ int wsum[4];
    int t = threadIdx.x, lane = t & 63, wv = t >> 6;
    h[t] = 0;
    __syncthreads();
    int vals[16]; bool vv[16];
#pragma unroll
    for (int k = 0; k < 16; k++) {
        int j = k * 256 + t;
        vv[k] = j < cnt_e;
        int x = vv[k] ? buf[j] : 0;
        vals[k] = x;
        if (vv[k]) atomicAdd(&h[x >> 16], 1);
    }
    __syncthreads();
    int v = h[t];   // own slot only
    int s = v;
#pragma unroll
    for (int off = 1; off < 64; off <<= 1) {
        int u = __shfl_up(s, off, 64);
        if (lane >= off) s += u;
    }
    if (lane == 63) wsum[wv] = s;
    __syncthreads();
    int woff = 0;
    for (int w = 0; w < wv; w++) woff += wsum[w];
    h[t] = s - v + woff;  // exclusive per-node offset (own slot; pre-sync safe)
    __syncthreads();
#pragma unroll
    for (int k = 0; k < 16; k++) {
        if (vv[k]) {
            int x = vals[k];
            int rl = x >> 16, c = x & 0xFFFF;
            int p = atomicAdd(&h[rl], 1);  // LDS cursor
            int gp = base + p;
            ssrc[gp] = (b << 8) + rl;
            sdst[gp] = c;
        }
    }
}

// ---------------------------------------------------------------------------
// emb_in (plain, fallback): h0[N,64] @ W[64,128] + b -> h (fp32), h_bf (bf16)
// ---------------------------------------------------------------------------
__global__ __launch_bounds__(256) void emb_in_kernel(
    const float* __restrict__ h0, const bf16_t* __restrict__ wp,
    const float* __restrict__ bias, float* __restrict__ h, bf16_t* __restrict__ h_bf)
{
    int t = threadIdx.x, wave = t >> 6, lane = t & 63;
    int quad = lane >> 4, col = lane & 15;
    int m0 = blockIdx.x * 64 + wave * 16;
    int ndc = min(m0 + col, N_NODES - 1);
    floatx4 acc[8] = {};
#pragma unroll
    for (int ks = 0; ks < 2; ks++) {
        const float* ap = h0 + ndc * 64 + ks * 32 + quad * 8;
        floatx4 f0 = *(const floatx4*)ap;
        floatx4 f1 = *(const floatx4*)(ap + 4);
        bf16x8 a;
#pragma unroll
        for (int j = 0; j < 4; j++) { a[j] = (bf16_t)f0[j]; a[j + 4] = (bf16_t)f1[j]; }
#pragma unroll
        for (int nt = 0; nt < 8; nt++) {
            bf16x8 b = ((const bf16x8*)wp)[(nt * 2 + ks) * 64 + lane];
            acc[nt] = __builtin_amdgcn_mfma_f32_16x16x32_bf16(a, b, acc[nt], 0, 0, 0);
        }
    }
#pragma unroll
    for (int r = 0; r < 4; r++) {
        int nd2 = m0 + quad * 4 + r;
        if (nd2 < N_NODES) {
#pragma unroll
            for (int nt = 0; nt < 8; nt++) {
                int n = nt * 16 + col;
                float x = acc[nt][r] + bias[n];
                h[nd2 * HID + n] = x;
                h_bf[nd2 * HID + n] = (bf16_t)x;
            }
        }
    }
}

// ---------------------------------------------------------------------------
// emb_in fused with layer-0 P precompute. P split: P_row fp32 [N][64] (the
// run-cached gather side), P_col bf16 [N][64] (+b1 folded; the RANDOM gather
// side -> half the random bytes in the edge kernel).
// ---------------------------------------------------------------------------
__global__ __launch_bounds__(256) void emb_in_p0_kernel(
    const float* __restrict__ h0, const bf16_t* __restrict__ wp,
    const float* __restrict__ bias, float* __restrict__ h, bf16_t* __restrict__ h_bf,
    const bf16_t* __restrict__ w1cat, const float* __restrict__ b1,
    float* __restrict__ Prow, bf16_t* __restrict__ Pcol)
{
    __shared__ __align__(16) bf16_t hl[4][16 * 136];
    int t = threadIdx.x, wave = t >> 6, lane = t & 63;
    int quad = lane >> 4, col = lane & 15;
    int m0 = blockIdx.x * 64 + wave * 16;
    int ndc = min(m0 + col, N_NODES - 1);
    floatx4 acc[8] = {};
#pragma unroll
    for (int ks = 0; ks < 2; ks++) {
        const float* ap = h0 + ndc * 64 + ks * 32 + quad * 8;
        floatx4 f0 = *(const floatx4*)ap;
        floatx4 f1 = *(const floatx4*)(ap + 4);
        bf16x8 a;
#pragma unroll
        for (int j = 0; j < 4; j++) { a[j] = (bf16_t)f0[j]; a[j + 4] = (bf16_t)f1[j]; }
#pragma unroll
        for (int nt = 0; nt < 8; nt++) {
            bf16x8 b = ((const bf16x8*)wp)[(nt * 2 + ks) * 64 + lane];
            acc[nt] = __builtin_amdgcn_mfma_f32_16x16x32_bf16(a, b, acc[nt], 0, 0, 0);
        }
    }
    bf16_t* myhl = hl[wave];
#pragma unroll
    for (int r = 0; r < 4; r++) {
        int nd2 = m0 + quad * 4 + r;
        bool valid = nd2 < N_NODES;
#pragma unroll
        for (int nt = 0; nt < 8; nt++) {
            int n = nt * 16 + col;
            if (valid) {
                float x = acc[nt][r] + bias[n];
                h[nd2 * HID + n] = x;
                bf16_t hb = (bf16_t)x;
                h_bf[nd2 * HID + n] = hb;
                myhl[(quad * 4 + r) * 136 + n] = hb;
            } else {
                myhl[(quad * 4 + r) * 136 + n] = (bf16_t)0.0f;
            }
        }
    }
    // no barrier: myhl is wave-local, DS ops in-order per wave
    floatx4 accp[8] = {};
#pragma unroll
    for (int ks = 0; ks < 4; ks++) {
        bf16x8 a = *(const bf16x8*)(myhl + col * 136 + ks * 32 + quad * 8);
#pragma unroll
        for (int nt = 0; nt < 8; nt++) {
            bf16x8 b = ((const bf16x8*)w1cat)[(nt * 4 + ks) * 64 + lane];
            accp[nt] = __builtin_amdgcn_mfma_f32_16x16x32_bf16(a, b, accp[nt], 0, 0, 0);
        }
    }
#pragma unroll
    for (int r = 0; r < 4; r++) {
        int nd2 = m0 + quad * 4 + r;
        if (nd2 < N_NODES) {
#pragma unroll
            for (int nt = 0; nt < 4; nt++) {
                int n = nt * 16 + col;
                Prow[nd2 * 64 + n] = accp[nt][r];
                Pcol[nd2 * 64 + n] = (bf16_t)(accp[nt + 4][r] + b1[n]);
            }
        }
    }
}

// ---------------------------------------------------------------------------
// Edge kernel over split P with cross-tile prefetch of the random-side Pcol
// and ballot-derived run-boundary combine. (round-6 form, unchanged)
// ---------------------------------------------------------------------------
__global__ __launch_bounds__(256, 4) void edge_kernel_pre(
    const float* __restrict__ Prow, const bf16_t* __restrict__ Pcol,
    const int* __restrict__ ssrc, const int* __restrict__ sdst,
    const int* __restrict__ m_ptr,
    const bf16_t* __restrict__ w2p, const float* __restrict__ b2,
    float* __restrict__ agg, float C)
{
    __shared__ __align__(16) bf16_t pool[4][64 * 40];  // per-wave mbT

    int t = threadIdx.x;
    int wave = t >> 6, lane = t & 63, quad = lane >> 4, col = lane & 15;
    bf16_t* mbT = pool[wave];  // messages transposed [n][e], stride 40

    float b2v[4];
#pragma unroll
    for (int nt = 0; nt < 4; nt++) b2v[nt] = b2[nt * 16 + col];

    int M = m_ptr[0];
    int ntiles = (M + 31) >> 5;
    int wid = blockIdx.x * 4 + wave, nw = gridDim.x * 4;
    if (wid >= ntiles) return;

    int sr = 0x7fffffff, ds = 0x7fffffff;
    { int p = wid * 32 + lane; if (lane < 32 && p < M) { sr = ssrc[p]; ds = sdst[p]; } }

    // prologue: prefetch current tile's Pcol fragments (random side)
    bf16x8 pcp[2][2];
#pragma unroll
    for (int m = 0; m < 2; m++) {
        int cN = min(__shfl(ds, m * 16 + col, 64), N_NODES - 1);
        const bf16_t* pc = Pcol + cN * 64 + quad * 8;
        pcp[m][0] = *(const bf16x8*)pc;
        pcp[m][1] = *(const bf16x8*)(pc + 32);
    }

    for (int tile = wid; tile < ntiles; tile += nw) {
        int tnc = min(tile + nw, ntiles - 1);
        int srn = 0x7fffffff, dsn = 0x7fffffff;
        { int p = tnc * 32 + lane; if (lane < 32 && p < M) { srn = ssrc[p]; dsn = sdst[p]; } }

        floatx4 acc2[2][4] = {};
#pragma unroll
        for (int m = 0; m < 2; m++) {
            int rN = min(__shfl(sr, m * 16 + col, 64), N_NODES - 1);
            const float* pr = Prow + rN * 64 + quad * 8;   // fp32, run-cached (L1)
            floatx4 fr[4];
            fr[0] = *(const floatx4*)pr;        fr[1] = *(const floatx4*)(pr + 4);
            fr[2] = *(const floatx4*)(pr + 32); fr[3] = *(const floatx4*)(pr + 36);
#pragma unroll
            for (int ks = 0; ks < 2; ks++) {
                bf16x8 a2;
#pragma unroll
                for (int j = 0; j < 4; j++) {
                    a2[j]     = (bf16_t)silu_f(fr[ks * 2][j]     + (float)pcp[m][ks][j]);
                    a2[j + 4] = (bf16_t)silu_f(fr[ks * 2 + 1][j] + (float)pcp[m][ks][j + 4]);
                }
#pragma unroll
                for (int nt = 0; nt < 4; nt++) {
                    bf16x8 b = ((const bf16x8*)w2p)[(nt * 2 + ks) * 64 + lane];
                    acc2[m][nt] = __builtin_amdgcn_mfma_f32_16x16x32_bf16(a2, b, acc2[m][nt], 0, 0, 0);
                }
            }
        }

        // prefetch NEXT tile's Pcol — lands under epilogue+combine
        bf16x8 pcn[2][2];
#pragma unroll
        for (int m = 0; m < 2; m++) {
            int cN = min(__shfl(dsn, m * 16 + col, 64), N_NODES - 1);
            const bf16_t* pc = Pcol + cN * 64 + quad * 8;
            pcn[m][0] = *(const bf16x8*)pc;
            pcn[m][1] = *(const bf16x8*)(pc + 32);
        }

        // epilogue2: messages TRANSPOSED mbT[n][e], 4 r-values per b64 write
#pragma unroll
        for (int m = 0; m < 2; m++)
#pragma unroll
            for (int nt = 0; nt < 4; nt++) {
                ushort4v pv;
#pragma unroll
                for (int r = 0; r < 4; r++) {
                    bf16_t bv = (bf16_t)(silu_f(acc2[m][nt][r] + b2v[nt]) * C);
                    pv[r] = __builtin_bit_cast(unsigned short, bv);
                }
                *(ushort4v*)(mbT + (nt * 16 + col) * 40 + m * 16 + quad * 4) = pv;
            }

        // run-boundary mask: one shfl + one ballot replaces 32 shfl+vcmp
        unsigned int bmask;
        {
            int prev = __shfl(sr, lane > 0 ? lane - 1 : 0, 64);
            bmask = (unsigned int)__ballot(lane > 0 && lane < 32 && sr != prev);
        }

        // combine: preload full column, then boundary-driven run accumulation
        {
            float mv[32];
#pragma unroll
            for (int i = 0; i < 4; i++) {
                bf16x8 v8 = *(const bf16x8*)(mbT + lane * 40 + i * 8);
#pragma unroll
                for (int j = 0; j < 8; j++) mv[i * 8 + j] = (float)v8[j];
            }
            int dp = __shfl(sr, 0, 64);
            float run = mv[0];
#pragma unroll
            for (int r = 1; r < 32; r++) {
                if (bmask & (1u << r)) {  // wave-uniform scalar test
                    if (dp < N_NODES) atomicAdd(agg + dp * EH + lane, run);
                    dp = __shfl(sr, r, 64);
                    run = mv[r];
                } else run += mv[r];
            }
            if (dp < N_NODES) atomicAdd(agg + dp * EH + lane, run);
        }

        sr = srn; ds = dsn;
#pragma unroll
        for (int m = 0; m < 2; m++) {
            pcp[m][0] = pcn[m][0];
            pcp[m][1] = pcn[m][1];
        }
    }
}

// ---------------------------------------------------------------------------
// Fallback (unsorted) edge kernel — used only if ws_size is too small.
// ---------------------------------------------------------------------------
__global__ __launch_bounds__(256) void edge_kernel(
    const bf16_t* __restrict__ h_bf, const int* __restrict__ edges,
    const int* __restrict__ mask,
    const bf16_t* __restrict__ w1p, const float* __restrict__ b1,
    const bf16_t* __restrict__ w2p, const float* __restrict__ b2,
    float* __restrict__ agg, float C)
{
    __shared__ __align__(16) bf16_t w1s[16384];
    __shared__ __align__(16) bf16_t w2s[4096];
    __shared__ __align__(16) bf16_t hl[4][16 * 72];

    int t = threadIdx.x;
#pragma unroll
    for (int i = 0; i < 8; i++)
        ((bf16x8*)w1s)[t + 256 * i] = ((const bf16x8*)w1p)[t + 256 * i];
#pragma unroll
    for (int i = 0; i < 2; i++)
        ((bf16x8*)w2s)[t + 256 * i] = ((const bf16x8*)w2p)[t + 256 * i];
    __syncthreads();

    int wave = t >> 6, lane = t & 63, quad = lane >> 4, col = lane & 15;
    bf16_t* myhl = hl[wave];

    float b1v[4], b2v[4];
#pragma unroll
    for (int nt = 0; nt < 4; nt++) { b1v[nt] = b1[nt * 16 + col]; b2v[nt] = b2[nt * 16 + col]; }

    const int ntile_cnt = N_EDGES / 64;
    for (int tile = blockIdx.x; tile < ntile_cnt; tile += gridDim.x) {
        int ebase = tile * 64 + wave * 16;
        int src = edges[ebase + col];
        int dst = edges[N_EDGES + ebase + col];

        floatx4 acc[4] = {};
#pragma unroll
        for (int ks = 0; ks < 8; ks++) {
            int idx = (ks < 4) ? src : dst;
            bf16x8 a = *(const bf16x8*)(h_bf + idx * HID + (ks & 3) * 32 + quad * 8);
#pragma unroll
            for (int nt = 0; nt < 4; nt++) {
                bf16x8 b = ((const bf16x8*)w1s)[(nt * 8 + ks) * 64 + lane];
                acc[nt] = __builtin_amdgcn_mfma_f32_16x16x32_bf16(a, b, acc[nt], 0, 0, 0);
            }
        }
#pragma unroll
        for (int nt = 0; nt < 4; nt++)
#pragma unroll
            for (int r = 0; r < 4; r++)
                myhl[(quad * 4 + r) * 72 + nt * 16 + col] = (bf16_t)silu_f(acc[nt][r] + b1v[nt]);
        __syncthreads();

        floatx4 acc2[4] = {};
#pragma unroll
        for (int ks = 0; ks < 2; ks++) {
            bf16x8 a = *(const bf16x8*)(myhl + col * 72 + ks * 32 + quad * 8);
#pragma unroll
            for (int nt = 0; nt < 4; nt++) {
                bf16x8 b = ((const bf16x8*)w2s)[(nt * 2 + ks) * 64 + lane];
                acc2[nt] = __builtin_amdgcn_mfma_f32_16x16x32_bf16(a, b, acc2[nt], 0, 0, 0);
            }
        }
#pragma unroll
        for (int r = 0; r < 4; r++) {
            int dest = edges[ebase + quad * 4 + r];
            if (mask[dest] != 0) {
                float* aggp = agg + dest * EH;
#pragma unroll
                for (int nt = 0; nt < 4; nt++) {
                    float x = acc2[nt][r] + b2v[nt];
                    atomicAdd(aggp + nt * 16 + col, silu_f(x) * C);
                }
            }
        }
        __syncthreads();
    }
}

// ---------------------------------------------------------------------------
// FUSED node kernel (layers 0..2): mask-gated node update for ALL nodes +
// next-layer P precompute from the updated h (staged in wave-local LDS).
// Replaces node_kernel_masked + pre_edge_kernel + the 3 compaction kernels.
// P inputs are the identical bf16 h_new values -> bit-identical results.
// ---------------------------------------------------------------------------
__global__ __launch_bounds__(256) void node_p_kernel(
    float* __restrict__ h, bf16_t* __restrict__ h_bf,
    float* __restrict__ agg, const int* __restrict__ mask,
    const bf16_t* __restrict__ w1p, const float* __restrict__ b1,
    const bf16_t* __restrict__ w2p, const float* __restrict__ b2,
    const bf16_t* __restrict__ w1cat, const float* __restrict__ b1n,
    float* __restrict__ Prow, bf16_t* __restrict__ Pcol)
{
    __shared__ __align__(16) bf16_t hl[4][16 * 136];
    int t = threadIdx.x, wave = t >> 6, lane = t & 63;
    int quad = lane >> 4, col = lane & 15;
    int m0 = blockIdx.x * 64 + wave * 16;
    int ndc = min(m0 + col, N_NODES - 1);

    floatx4 acc[8] = {};
#pragma unroll
    for (int ks = 0; ks < 6; ks++) {
        bf16x8 a;
        if (ks < 4) {
            a = *(const bf16x8*)(h_bf + ndc * HID + ks * 32 + quad * 8);
        } else {
            const float* ap = agg + ndc * EH + (ks - 4) * 32 + quad * 8;
            floatx4 f0 = *(const floatx4*)ap;
            floatx4 f1 = *(const floatx4*)(ap + 4);
#pragma unroll
            for (int j = 0; j < 4; j++) { a[j] = (bf16_t)f0[j]; a[j + 4] = (bf16_t)f1[j]; }
        }
#pragma unroll
        for (int nt = 0; nt < 8; nt++) {
            bf16x8 b = ((const bf16x8*)w1p)[(nt * 6 + ks) * 64 + lane];
            acc[nt] = __builtin_amdgcn_mfma_f32_16x16x32_bf16(a, b, acc[nt], 0, 0, 0);
        }
    }
    // zero this node's agg row for the next layer (unique unclamped owner;
    // unmasked rows were never written by the sorted edge kernel -> stay 0)
    {
        int nid = m0 + col;
        if (nid < N_NODES && mask[nid] != 0) {
            floatx4 z = {0.0f, 0.0f, 0.0f, 0.0f};
            float* zp = agg + nid * EH + quad * 8;
            *(floatx4*)zp = z; *(floatx4*)(zp + 4) = z;
            *(floatx4*)(zp + 32) = z; *(floatx4*)(zp + 36) = z;
        }
    }
    bf16_t* myhl = hl[wave];
#pragma unroll
    for (int nt = 0; nt < 8; nt++)
#pragma unroll
        for (int r = 0; r < 4; r++) {
            float x = acc[nt][r] + b1[nt * 16 + col];
            myhl[(quad * 4 + r) * 136 + nt * 16 + col] = (bf16_t)silu_f(x);
        }

    floatx4 acc2[8] = {};
#pragma unroll
    for (int ks = 0; ks < 4; ks++) {
        bf16x8 a = *(const bf16x8*)(myhl + col * 136 + ks * 32 + quad * 8);
#pragma unroll
        for (int nt = 0; nt < 8; nt++) {
            bf16x8 b = ((const bf16x8*)w2p)[(nt * 4 + ks) * 64 + lane];
            acc2[nt] = __builtin_amdgcn_mfma_f32_16x16x32_bf16(a, b, acc2[nt], 0, 0, 0);
        }
    }
    // write-back (masked) + stage h_new (all nodes) into myhl for the P GEMM
#pragma unroll
    for (int r = 0; r < 4; r++) {
        int nd2 = m0 + quad * 4 + r;
        bool valid = nd2 < N_NODES;
        bool upd = valid && mask[min(nd2, N_NODES - 1)] != 0;
        if (upd) {
#pragma unroll
            for (int nt = 0; nt < 8; nt++) {
                int n = nt * 16 + col;
                float hv = h[nd2 * HID + n] + acc2[nt][r] + b2[n];
                h[nd2 * HID + n] = hv;
                bf16_t hb = (bf16_t)hv;
                h_bf[nd2 * HID + n] = hb;
                myhl[(quad * 4 + r) * 136 + n] = hb;
            }
        } else {
#pragma unroll
            for (int nt = 0; nt < 8; nt++) {
                int n = nt * 16 + col;
                myhl[(quad * 4 + r) * 136 + n] =
                    valid ? h_bf[nd2 * HID + n] : (bf16_t)0.0f;
            }
        }
    }
    // next-layer P GEMM: P[n] = h_new[n] @ W1cat(next); split Prow/Pcol
    floatx4 accp[8] = {};
#pragma unroll
    for (int ks = 0; ks < 4; ks++) {
        bf16x8 a = *(const bf16x8*)(myhl + col * 136 + ks * 32 + quad * 8);
#pragma unroll
        for (int nt = 0; nt < 8; nt++) {
            bf16x8 b = ((const bf16x8*)w1cat)[(nt * 4 + ks) * 64 + lane];
            accp[nt] = __builtin_amdgcn_mfma_f32_16x16x32_bf16(a, b, accp[nt], 0, 0, 0);
        }
    }
#pragma unroll
    for (int r = 0; r < 4; r++) {
        int nd2 = m0 + quad * 4 + r;
        if (nd2 < N_NODES) {
#pragma unroll
            for (int nt = 0; nt < 4; nt++) {
                int n = nt * 16 + col;
                Prow[nd2 * 64 + n] = accp[nt][r];
                Pcol[nd2 * 64 + n] = (bf16_t)(accp[nt + 4][r] + b1n[n]);
            }
        }
    }
}

// ---------------------------------------------------------------------------
// Full node kernel (layer 3 + fallback): masked update + fused emb_out.
// ---------------------------------------------------------------------------
__global__ __launch_bounds__(256) void node_kernel(
    float* __restrict__ h, bf16_t* __restrict__ h_bf,
    float* __restrict__ agg, const int* __restrict__ mask,
    const bf16_t* __restrict__ w1p, const float* __restrict__ b1,
    const bf16_t* __restrict__ w2p, const float* __restrict__ b2,
    const bf16_t* __restrict__ wop, const float* __restrict__ bo,
    float* __restrict__ out)
{
    __shared__ __align__(16) bf16_t hl[4][16 * 136];
    int t = threadIdx.x, wave = t >> 6, lane = t & 63;
    int quad = lane >> 4, col = lane & 15;
    int m0 = blockIdx.x * 64 + wave * 16;
    int ndc = min(m0 + col, N_NODES - 1);

    floatx4 acc[8] = {};
#pragma unroll
    for (int ks = 0; ks < 6; ks++) {
        bf16x8 a;
        if (ks < 4) {
            a = *(const bf16x8*)(h_bf + ndc * HID + ks * 32 + quad * 8);
        } else {
            const float* ap = agg + ndc * EH + (ks - 4) * 32 + quad * 8;
            floatx4 f0 = *(const floatx4*)ap;
            floatx4 f1 = *(const floatx4*)(ap + 4);
#pragma unroll
            for (int j = 0; j < 4; j++) { a[j] = (bf16_t)f0[j]; a[j + 4] = (bf16_t)f1[j]; }
        }
#pragma unroll
        for (int nt = 0; nt < 8; nt++) {
            bf16x8 b = ((const bf16x8*)w1p)[(nt * 6 + ks) * 64 + lane];
            acc[nt] = __builtin_amdgcn_mfma_f32_16x16x32_bf16(a, b, acc[nt], 0, 0, 0);
        }
    }
    bf16_t* myhl = hl[wave];
#pragma unroll
    for (int nt = 0; nt < 8; nt++)
#pragma unroll
        for (int r = 0; r < 4; r++) {
            float x = acc[nt][r] + b1[nt * 16 + col];
            myhl[(quad * 4 + r) * 136 + nt * 16 + col] = (bf16_t)silu_f(x);
        }

    floatx4 acc2[8] = {};
#pragma unroll
    for (int ks = 0; ks < 4; ks++) {
        bf16x8 a = *(const bf16x8*)(myhl + col * 136 + ks * 32 + quad * 8);
#pragma unroll
        for (int nt = 0; nt < 8; nt++) {
            bf16x8 b = ((const bf16x8*)w2p)[(nt * 4 + ks) * 64 + lane];
            acc2[nt] = __builtin_amdgcn_mfma_f32_16x16x32_bf16(a, b, acc2[nt], 0, 0, 0);
        }
    }
#pragma unroll
    for (int r = 0; r < 4; r++) {
        int nd2 = m0 + quad * 4 + r;
        bool valid = nd2 < N_NODES;
        bool upd = valid && mask[min(nd2, N_NODES - 1)] != 0;
        if (upd) {
#pragma unroll
            for (int nt = 0; nt < 8; nt++) {
                int n = nt * 16 + col;
                float hv = h[nd2 * HID + n] + acc2[nt][r] + b2[n];
                h[nd2 * HID + n] = hv;
                bf16_t hb = (bf16_t)hv;
                h_bf[nd2 * HID + n] = hb;
                myhl[(quad * 4 + r) * 136 + n] = hb;
            }
        } else {
#pragma unroll
            for (int nt = 0; nt < 8; nt++) {
                int n = nt * 16 + col;
                myhl[(quad * 4 + r) * 136 + n] =
                    valid ? h_bf[nd2 * HID + n] : (bf16_t)0.0f;
            }
        }
    }
    floatx4 ao[4] = {};
#pragma unroll
    for (int ks = 0; ks < 4; ks++) {
        bf16x8 a = *(const bf16x8*)(myhl + col * 136 + ks * 32 + quad * 8);
#pragma unroll
        for (int nt = 0; nt < 4; nt++) {
            bf16x8 b = ((const bf16x8*)wop)[(nt * 4 + ks) * 64 + lane];
            ao[nt] = __builtin_amdgcn_mfma_f32_16x16x32_bf16(a, b, ao[nt], 0, 0, 0);
        }
    }
#pragma unroll
    for (int r = 0; r < 4; r++) {
        int nd2 = m0 + quad * 4 + r;
        if (nd2 < N_NODES) {
#pragma unroll
            for (int nt = 0; nt < 4; nt++) {
                int n = nt * 16 + col;
                out[nd2 * 64 + n] = ao[nt][r] + bo[n];
            }
        }
    }
}

extern "C" void kernel_launch(void* const* d_in, const int* in_sizes, int n_in,
                              void* d_out, int out_size, void* d_ws, size_t ws_size,
                              hipStream_t stream) {
    const float* h0        = (const float*)d_in[0];
    const int*   edges_a   = (const int*)d_in[1];
    const int*   edges_b   = (const int*)d_in[2];
    const int*   mask_a    = (const int*)d_in[3];
    const int*   mask_b    = (const int*)d_in[4];
    const float* emb_in_w  = (const float*)d_in[5];
    const float* emb_in_b  = (const float*)d_in[6];
    const float* emb_out_w = (const float*)d_in[7];
    const float* emb_out_b = (const float*)d_in[8];
    const float* ew1 = (const float*)d_in[9];
    const float* eb1 = (const float*)d_in[10];
    const float* ew2 = (const float*)d_in[11];
    const float* eb2 = (const float*)d_in[12];
    const float* nw1 = (const float*)d_in[13];
    const float* nb1 = (const float*)d_in[14];
    const float* nw2 = (const float*)d_in[15];
    const float* nb2 = (const float*)d_in[16];

    const size_t SZ_H = 25600000, SZ_HBF = 12800000, SZ_AGG = 12800000;
    const size_t SZ_PK = 655360;
    const size_t SZ_S = 3200000;
    const size_t SZ_GBUF = (size_t)2 * 256 * BKT_CAP * 4;  // 8 MB
    const size_t SZ_PROW = 12800000;  // P_row[N][64] fp32
    const size_t SZ_PCOL = 6400000;   // P_col[N][64] bf16

    char* ws = (char*)d_ws;
    size_t off = 0;
    float*  h    = (float*)(ws + off);  off += SZ_H;
    bf16_t* h_bf = (bf16_t*)(ws + off); off += SZ_HBF;
    bf16_t* pk   = (bf16_t*)(ws + off); off += SZ_PK;
    int* ssrc_a = (int*)(ws + off); off += SZ_S;
    int* sdst_a = (int*)(ws + off); off += SZ_S;
    int* ssrc_b = (int*)(ws + off); off += SZ_S;
    int* sdst_b = (int*)(ws + off); off += SZ_S;
    int* gbuf   = (int*)(ws + off); off += SZ_GBUF;
    int* gcur   = (int*)(ws + off); off += 2048;   // gcur|agg contiguous -> one memset
    float* agg  = (float*)(ws + off); off += SZ_AGG;
    int* bases  = (int*)(ws + off); off += 2048;
    int* mcnt_a = (int*)(ws + off); off += 256;
    int* mcnt_b = (int*)(ws + off); off += 256;
    float*  Prow = (float*)(ws + off);  off += SZ_PROW;
    bf16_t* Pcol = (bf16_t*)(ws + off); off += SZ_PCOL;
    bool ok = (ws_size >= off);  // full fast path

    bf16_t* pk_embin  = pk;
    bf16_t* pk_embout = pk + 8192;
    bf16_t* pk_ew1    = pk + 16384;
    bf16_t* pk_ew2    = pk + 81920;
    bf16_t* pk_nw1    = pk + 98304;
    bf16_t* pk_nw2    = pk + 196608;
    bf16_t* pk_ew1cat = pk + 262144;

    pack_all_kernel<<<160, 256, 0, stream>>>(emb_in_w, emb_out_w, ew1, ew2, nw1, nw2, pk);

    const int node_blocks = (N_NODES + 63) / 64;  // 782
    const int bkt_blocks = (N_EDGES + 2047) / 2048;  // 391
    if (ok) {
        hipMemsetAsync(gcur, 0, 2048 + SZ_AGG, stream);  // cursors + agg in one go
        bucketize_kernel<<<dim3(bkt_blocks, 2), 256, 0, stream>>>(
            edges_a, edges_b, mask_a, mask_b, gcur, gbuf);
        bucket_scan_kernel<<<2, 256, 0, stream>>>(gcur, bases, mcnt_a, mcnt_b);
        bucket_sort_kernel<<<dim3(NCH, 2), 256, 0, stream>>>(
            gcur, gbuf, bases, ssrc_a, sdst_a, ssrc_b, sdst_b);
        emb_in_p0_kernel<<<node_blocks, 256, 0, stream>>>(
            h0, pk_embin, emb_in_b, h, h_bf, pk_ew1cat, eb1, Prow, Pcol);
    } else {
        hipMemsetAsync(agg, 0, SZ_AGG, stream);
        emb_in_kernel<<<node_blocks, 256, 0, stream>>>(h0, pk_embin, emb_in_b, h, h_bf);
    }

    for (int l = 0; l < 4; l++) {
        const int* mask = (l & 1) ? mask_b : mask_a;
        float C = (l & 1) ? 0.03125f : 1.0f;
        if (ok) {
            const int* ssrc = (l & 1) ? ssrc_b : ssrc_a;
            const int* sdst = (l & 1) ? sdst_b : sdst_a;
            const int* mp   = (l & 1) ? mcnt_b : mcnt_a;
            edge_kernel_pre<<<1024, 256, 0, stream>>>(Prow, Pcol, ssrc, sdst, mp,
                                                      pk_ew2 + l * 4096, eb2 + l * 64,
                                                      agg, C);
            if (l < 3) {
                // fused: node update (mask-gated, all nodes) + layer l+1 P
                node_p_kernel<<<node_blocks, 256, 0, stream>>>(
                    h, h_bf, agg, mask,
                    pk_nw1 + l * 24576, nb1 + l * 128,
                    pk_nw2 + l * 16384, nb2 + l * 128,
                    pk_ew1cat + (l + 1) * 16384, eb1 + (l + 1) * 64,
                    Prow, Pcol);
            } else {
                node_kernel<<<node_blocks, 256, 0, stream>>>(
                    h, h_bf, agg, mask,
                    pk_nw1 + 3 * 24576, nb1 + 3 * 128,
                    pk_nw2 + 3 * 16384, nb2 + 3 * 128,
                    pk_embout, emb_out_b, (float*)d_out);
            }
        } else {
            const int* edges = (l & 1) ? edges_b : edges_a;
            edge_kernel<<<768, 256, 0, stream>>>(h_bf, edges, mask,
                                                 pk_ew1 + l * 16384, eb1 + l * 64,
                                                 pk_ew2 + l * 4096,  eb2 + l * 64,
                                                 agg, C);
            node_kernel<<<node_blocks, 256, 0, stream>>>(h, h_bf, agg, mask,
                                                         pk_nw1 + l * 24576, nb1 + l * 128,
                                                         pk_nw2 + l * 16384, nb2 + l * 128,
                                                         pk_embout, emb_out_b, (float*)d_out);
            if (l < 3) hipMemsetAsync(agg, 0, SZ_AGG, stream);
        }
    }
}

// Round 8
// 363.647 us; speedup vs baseline: 1.1173x; 1.1173x over previous
//
#include <hip/hip_runtime.h>
#include <cstdint>

typedef __bf16 bf16_t;
typedef bf16_t bf16x8 __attribute__((ext_vector_type(8)));
typedef float floatx4 __attribute__((ext_vector_type(4)));
typedef unsigned short ushort4v __attribute__((ext_vector_type(4)));

constexpr int N_NODES = 50000;
constexpr int N_EDGES = 800000;
constexpr int HID = 128;
constexpr int EH = 64;
constexpr int NCH = (N_NODES + 255) / 256;  // 196 buckets
constexpr int BKT_CAP = 4096;               // slots per bucket (mean ~2048)

__device__ __forceinline__ float silu_f(float x) {
    return x * __builtin_amdgcn_rcpf(1.0f + __expf(-x));
}

// ---------------------------------------------------------------------------
// Fused weight pack: all 6 weight tensors -> bf16 MFMA B-fragment order.
// Extra region at pk+262144: ew1 repacked as a fused [128 x 128] B so that
// P[n] = [ h@W1_top | h@W1_bot ] comes out of ONE K=128 GEMM per node.
// ---------------------------------------------------------------------------
__global__ __launch_bounds__(256) void pack_all_kernel(
    const float* __restrict__ embin, const float* __restrict__ embout,
    const float* __restrict__ ew1, const float* __restrict__ ew2,
    const float* __restrict__ nw1, const float* __restrict__ nw2,
    bf16_t* __restrict__ pk)
{
    int t = blockIdx.x * 256 + threadIdx.x;
    if (t >= 32768) {
        t -= 32768;
        int lane = t & 63, chunk = t >> 6;
        int ks = chunk & 3, nt = (chunk >> 2) & 7, l = chunk >> 5;
        int quad = lane >> 4, coln = lane & 15;
        const float* Wl = ew1 + l * 256 * 64;
        int kb = (nt >= 4 ? 128 : 0) + ks * 32 + quad * 8;
        int nc = (nt & 3) * 16 + coln;
        bf16x8 v;
#pragma unroll
        for (int j = 0; j < 8; j++) v[j] = (bf16_t)Wl[(kb + j) * 64 + nc];
        *(bf16x8*)(pk + 262144 + t * 8) = v;
        return;
    }
    const float* W; int K, Nc; int base; bf16_t* out;
    if (t < 1024)       { W = embin;  K = 64;  Nc = 128; base = 0;     out = pk; }
    else if (t < 2048)  { W = embout; K = 128; Nc = 64;  base = 1024;  out = pk + 8192; }
    else if (t < 10240) { W = ew1;    K = 256; Nc = 64;  base = 2048;  out = pk + 16384; }
    else if (t < 12288) { W = ew2;    K = 64;  Nc = 64;  base = 10240; out = pk + 81920; }
    else if (t < 24576) { W = nw1;    K = 192; Nc = 128; base = 12288; out = pk + 98304; }
    else                { W = nw2;    K = 128; Nc = 128; base = 24576; out = pk + 196608; }
    t -= base;
    int KS = K >> 5, NT = Nc >> 4;
    int lane = t & 63;
    int chunk = t >> 6;
    int ks = chunk % KS;
    int nt = (chunk / KS) % NT;
    int l  = chunk / (KS * NT);
    int quad = lane >> 4, coln = lane & 15;
    const float* Wl = W + l * K * Nc;
    bf16x8 v;
#pragma unroll
    for (int j = 0; j < 8; j++)
        v[j] = (bf16_t)Wl[(ks * 32 + quad * 8 + j) * Nc + nt * 16 + coln];
    *(bf16x8*)(out + t * 8) = v;
}

// ---------------------------------------------------------------------------
// SORT pass 1: bucketize masked edges by dst>>8 into fixed 4096-slot bucket
// regions. Per block: LDS histogram -> ONE global atomic per bucket (range
// reserve) -> LDS-cursor append of packed (r&255)<<16 | c.
// ---------------------------------------------------------------------------
__global__ __launch_bounds__(256) void bucketize_kernel(
    const int* __restrict__ ea, const int* __restrict__ eb,
    const int* __restrict__ ma, const int* __restrict__ mb,
    int* __restrict__ gcur, int* __restrict__ gbuf)
{
    int g = blockIdx.y;
    const int* e    = g ? eb : ea;
    const int* mask = g ? mb : ma;
    int* cur = gcur + g * 256;
    int* buf = gbuf + g * 256 * BKT_CAP;
    __shared__ int cnt[256];
    int t = threadIdx.x;
    cnt[t] = 0;
    __syncthreads();
    int base = blockIdx.x * 2048;
    int r[8], c[8]; bool v[8];
#pragma unroll
    for (int k = 0; k < 8; k++) {
        int i = base + k * 256 + t;
        bool ok = i < N_EDGES;
        int ii = ok ? i : 0;
        int rr = e[ii];
        int cc = e[N_EDGES + ii];
        v[k] = ok && (mask[rr] != 0);
        r[k] = rr; c[k] = cc;
        if (v[k]) atomicAdd(&cnt[rr >> 8], 1);
    }
    __syncthreads();
    int lc = cnt[t];
    int gb = 0;
    if (lc > 0) gb = atomicAdd(&cur[t], lc);  // reserve contiguous range
    cnt[t] = gb;                              // own slot only; safe pre-sync
    __syncthreads();
#pragma unroll
    for (int k = 0; k < 8; k++) {
        if (v[k]) {
            int bkt = r[k] >> 8;
            int p = atomicAdd(&cnt[bkt], 1);  // LDS cursor
            if (p < BKT_CAP)
                buf[bkt * BKT_CAP + p] = ((r[k] & 255) << 16) | c[k];
        }
    }
}

// ---------------------------------------------------------------------------
// SORT tiny scan: exclusive scan of 196 bucket counts per graph -> bases + M.
// ---------------------------------------------------------------------------
__global__ __launch_bounds__(256) void bucket_scan_kernel(
    const int* __restrict__ gcur, int* __restrict__ bases,
    int* __restrict__ mcnt_a, int* __restrict__ mcnt_b)
{
    int g = blockIdx.x;
    const int* cur = gcur + g * 256;
    int t = threadIdx.x, lane = t & 63, wv = t >> 6;
    int v = (t < NCH) ? min(cur[t], BKT_CAP) : 0;
    int s = v;
#pragma unroll
    for (int off = 1; off < 64; off <<= 1) {
        int u = __shfl_up(s, off, 64);
        if (lane >= off) s += u;
    }
    __shared__ int wsum[4];
    if (lane == 63) wsum[wv] = s;
    __syncthreads();
    int woff = 0;
    for (int w = 0; w < wv; w++) woff += wsum[w];
    int excl = s - v + woff;
    bases[g * 256 + t] = excl;
    if (t == NCH - 1) *(g ? mcnt_b : mcnt_a) = excl + v;
}

// ---------------------------------------------------------------------------
// SORT pass 2: per-bucket counting sort fully in LDS. ZERO global atomics.
// ---------------------------------------------------------------------------
__global__ __launch_bounds__(256) void bucket_sort_kernel(
    const int* __restrict__ gcur, const int* __restrict__ gbuf,
    const int* __restrict__ bases,
    int* __restrict__ ssrc_a, int* __restrict__ sdst_a,
    int* __restrict__ ssrc_b, int* __restrict__ sdst_b)
{
    int g = blockIdx.y, b = blockIdx.x;
    const int* buf = gbuf + g * 256 * BKT_CAP + b * BKT_CAP;
    int* ssrc = g ? ssrc_b : ssrc_a;
    int* sdst = g ? sdst_b : sdst_a;
    int cnt_e = min(gcur[g * 256 + b], BKT_CAP);
    int base = bases[g * 256 + b];
    __shared__ int h[256];
    __shared__ int wsum[4];
    int t = threadIdx.x, lane = t & 63, wv = t >> 6;
    h[t] = 0;
    __syncthreads();
    int vals[16]; bool vv[16];
#pragma unroll
    for (int k = 0; k < 16; k++) {
        int j = k * 256 + t;
        vv[k] = j < cnt_e;
        int x = vv[k] ? buf[j] : 0;
        vals[k] = x;
        if (vv[k]) atomicAdd(&h[x >> 16], 1);
    }
    __syncthreads();
    int v = h[t];   // own slot only
    int s = v;
#pragma unroll
    for (int off = 1; off < 64; off <<= 1) {
        int u = __shfl_up(s, off, 64);
        if (lane >= off) s += u;
    }
    if (lane == 63) wsum[wv] = s;
    __syncthreads();
    int woff = 0;
    for (int w = 0; w < wv; w++) woff += wsum[w];
    h[t] = s - v + woff;  // exclusive per-node offset (own slot; pre-sync safe)
    __syncthreads();
#pragma unroll
    for (int k = 0; k < 16; k++) {
        if (vv[k]) {
            int x = vals[k];
            int rl = x >> 16, c = x & 0xFFFF;
            int p = atomicAdd(&h[rl], 1);  // LDS cursor
            int gp = base + p;
            ssrc[gp] = (b << 8) + rl;
            sdst[gp] = c;
        }
    }
}

// per-256-chunk sums of mask (for masked-node compaction)
__global__ __launch_bounds__(256) void scan_phase1(
    const int* __restrict__ bins_a, const int* __restrict__ bins_b,
    int* __restrict__ bs_a, int* __restrict__ bs_b) {
    const int* bins = blockIdx.y ? bins_b : bins_a;
    int* bs = blockIdx.y ? bs_b : bs_a;
    int i = blockIdx.x * 256 + threadIdx.x;
    int v = (i < N_NODES) ? (bins[i] != 0 ? bins[i] : 0) : 0;
#pragma unroll
    for (int off = 32; off; off >>= 1) v += __shfl_down(v, off, 64);
    __shared__ int ws_[4];
    int lane = threadIdx.x & 63, wv = threadIdx.x >> 6;
    if (lane == 0) ws_[wv] = v;
    __syncthreads();
    if (threadIdx.x == 0) bs[blockIdx.x] = ws_[0] + ws_[1] + ws_[2] + ws_[3];
}

// scan 196 mask-chunk sums in place; write total to cnt[0]
__global__ __launch_bounds__(256) void mask_scan2(
    int* __restrict__ ms_a, int* __restrict__ ms_b,
    int* __restrict__ cnt_a, int* __restrict__ cnt_b) {
    int* ms = blockIdx.x ? ms_b : ms_a;
    int* cnt = blockIdx.x ? cnt_b : cnt_a;
    int t = threadIdx.x, lane = t & 63, wv = t >> 6;
    int v = (t < NCH) ? ms[t] : 0;
    int s = v;
#pragma unroll
    for (int off = 1; off < 64; off <<= 1) {
        int u = __shfl_up(s, off, 64);
        if (lane >= off) s += u;
    }
    __shared__ int wsum[4];
    if (lane == 63) wsum[wv] = s;
    __syncthreads();
    int woff = 0;
    for (int w = 0; w < wv; w++) woff += wsum[w];
    int excl = s - v + woff;
    if (t < NCH) ms[t] = excl;
    if (t == NCH - 1) cnt[0] = excl + v;
}

// ballot-based masked-node compaction (list in ascending node order)
__global__ __launch_bounds__(256) void compact_kernel(
    const int* __restrict__ ma, const int* __restrict__ mb,
    const int* __restrict__ ms_a, const int* __restrict__ ms_b,
    int* __restrict__ la, int* __restrict__ lb) {
    const int* mask = blockIdx.y ? mb : ma;
    const int* ms = blockIdx.y ? ms_b : ms_a;
    int* list = blockIdx.y ? lb : la;
    int i = blockIdx.x * 256 + threadIdx.x;
    int t = threadIdx.x, lane = t & 63, wv = t >> 6;
    int m = (i < N_NODES) ? (mask[i] != 0) : 0;
    unsigned long long bal = __ballot(m != 0);
    int pos = (int)__popcll(bal & ((1ull << lane) - 1ull));
    __shared__ int wsum[4];
    if (lane == 63) wsum[wv] = pos + m;
    __syncthreads();
    int woff = 0;
    for (int w = 0; w < wv; w++) woff += wsum[w];
    if (m) list[ms[blockIdx.x] + woff + pos] = i;
}

// ---------------------------------------------------------------------------
// emb_in (plain, fallback): h0[N,64] @ W[64,128] + b -> h (fp32), h_bf (bf16)
// ---------------------------------------------------------------------------
__global__ __launch_bounds__(256) void emb_in_kernel(
    const float* __restrict__ h0, const bf16_t* __restrict__ wp,
    const float* __restrict__ bias, float* __restrict__ h, bf16_t* __restrict__ h_bf)
{
    int t = threadIdx.x, wave = t >> 6, lane = t & 63;
    int quad = lane >> 4, col = lane & 15;
    int m0 = blockIdx.x * 64 + wave * 16;
    int ndc = min(m0 + col, N_NODES - 1);
    floatx4 acc[8] = {};
#pragma unroll
    for (int ks = 0; ks < 2; ks++) {
        const float* ap = h0 + ndc * 64 + ks * 32 + quad * 8;
        floatx4 f0 = *(const floatx4*)ap;
        floatx4 f1 = *(const floatx4*)(ap + 4);
        bf16x8 a;
#pragma unroll
        for (int j = 0; j < 4; j++) { a[j] = (bf16_t)f0[j]; a[j + 4] = (bf16_t)f1[j]; }
#pragma unroll
        for (int nt = 0; nt < 8; nt++) {
            bf16x8 b = ((const bf16x8*)wp)[(nt * 2 + ks) * 64 + lane];
            acc[nt] = __builtin_amdgcn_mfma_f32_16x16x32_bf16(a, b, acc[nt], 0, 0, 0);
        }
    }
#pragma unroll
    for (int r = 0; r < 4; r++) {
        int nd2 = m0 + quad * 4 + r;
        if (nd2 < N_NODES) {
#pragma unroll
            for (int nt = 0; nt < 8; nt++) {
                int n = nt * 16 + col;
                float x = acc[nt][r] + bias[n];
                h[nd2 * HID + n] = x;
                h_bf[nd2 * HID + n] = (bf16_t)x;
            }
        }
    }
}

// ---------------------------------------------------------------------------
// emb_in fused with layer-0 P precompute. P split: P_row fp32 [N][64] (the
// run-cached gather side), P_col bf16 [N][64] (+b1 folded; the RANDOM gather
// side -> half the random bytes in the edge kernel).
// ---------------------------------------------------------------------------
__global__ __launch_bounds__(256) void emb_in_p0_kernel(
    const float* __restrict__ h0, const bf16_t* __restrict__ wp,
    const float* __restrict__ bias, float* __restrict__ h, bf16_t* __restrict__ h_bf,
    const bf16_t* __restrict__ w1cat, const float* __restrict__ b1,
    float* __restrict__ Prow, bf16_t* __restrict__ Pcol)
{
    __shared__ __align__(16) bf16_t hl[4][16 * 136];
    int t = threadIdx.x, wave = t >> 6, lane = t & 63;
    int quad = lane >> 4, col = lane & 15;
    int m0 = blockIdx.x * 64 + wave * 16;
    int ndc = min(m0 + col, N_NODES - 1);
    floatx4 acc[8] = {};
#pragma unroll
    for (int ks = 0; ks < 2; ks++) {
        const float* ap = h0 + ndc * 64 + ks * 32 + quad * 8;
        floatx4 f0 = *(const floatx4*)ap;
        floatx4 f1 = *(const floatx4*)(ap + 4);
        bf16x8 a;
#pragma unroll
        for (int j = 0; j < 4; j++) { a[j] = (bf16_t)f0[j]; a[j + 4] = (bf16_t)f1[j]; }
#pragma unroll
        for (int nt = 0; nt < 8; nt++) {
            bf16x8 b = ((const bf16x8*)wp)[(nt * 2 + ks) * 64 + lane];
            acc[nt] = __builtin_amdgcn_mfma_f32_16x16x32_bf16(a, b, acc[nt], 0, 0, 0);
        }
    }
    bf16_t* myhl = hl[wave];
#pragma unroll
    for (int r = 0; r < 4; r++) {
        int nd2 = m0 + quad * 4 + r;
        bool valid = nd2 < N_NODES;
#pragma unroll
        for (int nt = 0; nt < 8; nt++) {
            int n = nt * 16 + col;
            if (valid) {
                float x = acc[nt][r] + bias[n];
                h[nd2 * HID + n] = x;
                bf16_t hb = (bf16_t)x;
                h_bf[nd2 * HID + n] = hb;
                myhl[(quad * 4 + r) * 136 + n] = hb;
            } else {
                myhl[(quad * 4 + r) * 136 + n] = (bf16_t)0.0f;
            }
        }
    }
    // no barrier: myhl is wave-local, DS ops in-order per wave
    floatx4 accp[8] = {};
#pragma unroll
    for (int ks = 0; ks < 4; ks++) {
        bf16x8 a = *(const bf16x8*)(myhl + col * 136 + ks * 32 + quad * 8);
#pragma unroll
        for (int nt = 0; nt < 8; nt++) {
            bf16x8 b = ((const bf16x8*)w1cat)[(nt * 4 + ks) * 64 + lane];
            accp[nt] = __builtin_amdgcn_mfma_f32_16x16x32_bf16(a, b, accp[nt], 0, 0, 0);
        }
    }
#pragma unroll
    for (int r = 0; r < 4; r++) {
        int nd2 = m0 + quad * 4 + r;
        if (nd2 < N_NODES) {
#pragma unroll
            for (int nt = 0; nt < 4; nt++) {
                int n = nt * 16 + col;
                Prow[nd2 * 64 + n] = accp[nt][r];
                Pcol[nd2 * 64 + n] = (bf16_t)(accp[nt + 4][r] + b1[n]);
            }
        }
    }
}

// ---------------------------------------------------------------------------
// Per-layer node precompute (layers 1..3): split P_row fp32 / P_col bf16.
// ---------------------------------------------------------------------------
__global__ __launch_bounds__(256) void pre_edge_kernel(
    const bf16_t* __restrict__ h_bf, const bf16_t* __restrict__ w1cat,
    const float* __restrict__ b1, float* __restrict__ Prow, bf16_t* __restrict__ Pcol)
{
    int t = threadIdx.x, wave = t >> 6, lane = t & 63;
    int quad = lane >> 4, col = lane & 15;
    int m0 = blockIdx.x * 64 + wave * 16;
    int ndc = min(m0 + col, N_NODES - 1);
    // hoist all 4 A-fragment loads (memory-level parallelism)
    bf16x8 af[4];
#pragma unroll
    for (int ks = 0; ks < 4; ks++)
        af[ks] = *(const bf16x8*)(h_bf + ndc * HID + ks * 32 + quad * 8);
    floatx4 acc[8] = {};
#pragma unroll
    for (int ks = 0; ks < 4; ks++) {
#pragma unroll
        for (int nt = 0; nt < 8; nt++) {
            bf16x8 b = ((const bf16x8*)w1cat)[(nt * 4 + ks) * 64 + lane];
            acc[nt] = __builtin_amdgcn_mfma_f32_16x16x32_bf16(af[ks], b, acc[nt], 0, 0, 0);
        }
    }
#pragma unroll
    for (int r = 0; r < 4; r++) {
        int nd2 = m0 + quad * 4 + r;
        if (nd2 < N_NODES) {
#pragma unroll
            for (int nt = 0; nt < 4; nt++) {
                int n = nt * 16 + col;
                Prow[nd2 * 64 + n] = acc[nt][r];
                Pcol[nd2 * 64 + n] = (bf16_t)(acc[nt + 4][r] + b1[n]);
            }
        }
    }
}

// ---------------------------------------------------------------------------
// Edge kernel over split P with cross-tile prefetch of the random-side Pcol
// and ballot-derived run-boundary combine. (round-6 form, unchanged)
// ---------------------------------------------------------------------------
__global__ __launch_bounds__(256, 4) void edge_kernel_pre(
    const float* __restrict__ Prow, const bf16_t* __restrict__ Pcol,
    const int* __restrict__ ssrc, const int* __restrict__ sdst,
    const int* __restrict__ m_ptr,
    const bf16_t* __restrict__ w2p, const float* __restrict__ b2,
    float* __restrict__ agg, float C)
{
    __shared__ __align__(16) bf16_t pool[4][64 * 40];  // per-wave mbT

    int t = threadIdx.x;
    int wave = t >> 6, lane = t & 63, quad = lane >> 4, col = lane & 15;
    bf16_t* mbT = pool[wave];  // messages transposed [n][e], stride 40

    float b2v[4];
#pragma unroll
    for (int nt = 0; nt < 4; nt++) b2v[nt] = b2[nt * 16 + col];

    int M = m_ptr[0];
    int ntiles = (M + 31) >> 5;
    int wid = blockIdx.x * 4 + wave, nw = gridDim.x * 4;
    if (wid >= ntiles) return;

    int sr = 0x7fffffff, ds = 0x7fffffff;
    { int p = wid * 32 + lane; if (lane < 32 && p < M) { sr = ssrc[p]; ds = sdst[p]; } }

    // prologue: prefetch current tile's Pcol fragments (random side)
    bf16x8 pcp[2][2];
#pragma unroll
    for (int m = 0; m < 2; m++) {
        int cN = min(__shfl(ds, m * 16 + col, 64), N_NODES - 1);
        const bf16_t* pc = Pcol + cN * 64 + quad * 8;
        pcp[m][0] = *(const bf16x8*)pc;
        pcp[m][1] = *(const bf16x8*)(pc + 32);
    }

    for (int tile = wid; tile < ntiles; tile += nw) {
        int tnc = min(tile + nw, ntiles - 1);
        int srn = 0x7fffffff, dsn = 0x7fffffff;
        { int p = tnc * 32 + lane; if (lane < 32 && p < M) { srn = ssrc[p]; dsn = sdst[p]; } }

        floatx4 acc2[2][4] = {};
#pragma unroll
        for (int m = 0; m < 2; m++) {
            int rN = min(__shfl(sr, m * 16 + col, 64), N_NODES - 1);
            const float* pr = Prow + rN * 64 + quad * 8;   // fp32, run-cached (L1)
            floatx4 fr[4];
            fr[0] = *(const floatx4*)pr;        fr[1] = *(const floatx4*)(pr + 4);
            fr[2] = *(const floatx4*)(pr + 32); fr[3] = *(const floatx4*)(pr + 36);
#pragma unroll
            for (int ks = 0; ks < 2; ks++) {
                bf16x8 a2;
#pragma unroll
                for (int j = 0; j < 4; j++) {
                    a2[j]     = (bf16_t)silu_f(fr[ks * 2][j]     + (float)pcp[m][ks][j]);
                    a2[j + 4] = (bf16_t)silu_f(fr[ks * 2 + 1][j] + (float)pcp[m][ks][j + 4]);
                }
#pragma unroll
                for (int nt = 0; nt < 4; nt++) {
                    bf16x8 b = ((const bf16x8*)w2p)[(nt * 2 + ks) * 64 + lane];
                    acc2[m][nt] = __builtin_amdgcn_mfma_f32_16x16x32_bf16(a2, b, acc2[m][nt], 0, 0, 0);
                }
            }
        }

        // prefetch NEXT tile's Pcol — lands under epilogue+combine
        bf16x8 pcn[2][2];
#pragma unroll
        for (int m = 0; m < 2; m++) {
            int cN = min(__shfl(dsn, m * 16 + col, 64), N_NODES - 1);
            const bf16_t* pc = Pcol + cN * 64 + quad * 8;
            pcn[m][0] = *(const bf16x8*)pc;
            pcn[m][1] = *(const bf16x8*)(pc + 32);
        }

        // epilogue2: messages TRANSPOSED mbT[n][e], 4 r-values per b64 write
#pragma unroll
        for (int m = 0; m < 2; m++)
#pragma unroll
            for (int nt = 0; nt < 4; nt++) {
                ushort4v pv;
#pragma unroll
                for (int r = 0; r < 4; r++) {
                    bf16_t bv = (bf16_t)(silu_f(acc2[m][nt][r] + b2v[nt]) * C);
                    pv[r] = __builtin_bit_cast(unsigned short, bv);
                }
                *(ushort4v*)(mbT + (nt * 16 + col) * 40 + m * 16 + quad * 4) = pv;
            }

        // run-boundary mask: one shfl + one ballot replaces 32 shfl+vcmp
        unsigned int bmask;
        {
            int prev = __shfl(sr, lane > 0 ? lane - 1 : 0, 64);
            bmask = (unsigned int)__ballot(lane > 0 && lane < 32 && sr != prev);
        }

        // combine: preload full column, then boundary-driven run accumulation
        {
            float mv[32];
#pragma unroll
            for (int i = 0; i < 4; i++) {
                bf16x8 v8 = *(const bf16x8*)(mbT + lane * 40 + i * 8);
#pragma unroll
                for (int j = 0; j < 8; j++) mv[i * 8 + j] = (float)v8[j];
            }
            int dp = __shfl(sr, 0, 64);
            float run = mv[0];
#pragma unroll
            for (int r = 1; r < 32; r++) {
                if (bmask & (1u << r)) {  // wave-uniform scalar test
                    if (dp < N_NODES) atomicAdd(agg + dp * EH + lane, run);
                    dp = __shfl(sr, r, 64);
                    run = mv[r];
                } else run += mv[r];
            }
            if (dp < N_NODES) atomicAdd(agg + dp * EH + lane, run);
        }

        sr = srn; ds = dsn;
#pragma unroll
        for (int m = 0; m < 2; m++) {
            pcp[m][0] = pcn[m][0];
            pcp[m][1] = pcn[m][1];
        }
    }
}

// ---------------------------------------------------------------------------
// Fallback (unsorted) edge kernel — used only if ws_size is too small.
// ---------------------------------------------------------------------------
__global__ __launch_bounds__(256) void edge_kernel(
    const bf16_t* __restrict__ h_bf, const int* __restrict__ edges,
    const int* __restrict__ mask,
    const bf16_t* __restrict__ w1p, const float* __restrict__ b1,
    const bf16_t* __restrict__ w2p, const float* __restrict__ b2,
    float* __restrict__ agg, float C)
{
    __shared__ __align__(16) bf16_t w1s[16384];
    __shared__ __align__(16) bf16_t w2s[4096];
    __shared__ __align__(16) bf16_t hl[4][16 * 72];

    int t = threadIdx.x;
#pragma unroll
    for (int i = 0; i < 8; i++)
        ((bf16x8*)w1s)[t + 256 * i] = ((const bf16x8*)w1p)[t + 256 * i];
#pragma unroll
    for (int i = 0; i < 2; i++)
        ((bf16x8*)w2s)[t + 256 * i] = ((const bf16x8*)w2p)[t + 256 * i];
    __syncthreads();

    int wave = t >> 6, lane = t & 63, quad = lane >> 4, col = lane & 15;
    bf16_t* myhl = hl[wave];

    float b1v[4], b2v[4];
#pragma unroll
    for (int nt = 0; nt < 4; nt++) { b1v[nt] = b1[nt * 16 + col]; b2v[nt] = b2[nt * 16 + col]; }

    const int ntile_cnt = N_EDGES / 64;
    for (int tile = blockIdx.x; tile < ntile_cnt; tile += gridDim.x) {
        int ebase = tile * 64 + wave * 16;
        int src = edges[ebase + col];
        int dst = edges[N_EDGES + ebase + col];

        floatx4 acc[4] = {};
#pragma unroll
        for (int ks = 0; ks < 8; ks++) {
            int idx = (ks < 4) ? src : dst;
            bf16x8 a = *(const bf16x8*)(h_bf + idx * HID + (ks & 3) * 32 + quad * 8);
#pragma unroll
            for (int nt = 0; nt < 4; nt++) {
                bf16x8 b = ((const bf16x8*)w1s)[(nt * 8 + ks) * 64 + lane];
                acc[nt] = __builtin_amdgcn_mfma_f32_16x16x32_bf16(a, b, acc[nt], 0, 0, 0);
            }
        }
#pragma unroll
        for (int nt = 0; nt < 4; nt++)
#pragma unroll
            for (int r = 0; r < 4; r++)
                myhl[(quad * 4 + r) * 72 + nt * 16 + col] = (bf16_t)silu_f(acc[nt][r] + b1v[nt]);
        __syncthreads();

        floatx4 acc2[4] = {};
#pragma unroll
        for (int ks = 0; ks < 2; ks++) {
            bf16x8 a = *(const bf16x8*)(myhl + col * 72 + ks * 32 + quad * 8);
#pragma unroll
            for (int nt = 0; nt < 4; nt++) {
                bf16x8 b = ((const bf16x8*)w2s)[(nt * 2 + ks) * 64 + lane];
                acc2[nt] = __builtin_amdgcn_mfma_f32_16x16x32_bf16(a, b, acc2[nt], 0, 0, 0);
            }
        }
#pragma unroll
        for (int r = 0; r < 4; r++) {
            int dest = edges[ebase + quad * 4 + r];
            if (mask[dest] != 0) {
                float* aggp = agg + dest * EH;
#pragma unroll
                for (int nt = 0; nt < 4; nt++) {
                    float x = acc2[nt][r] + b2v[nt];
                    atomicAdd(aggp + nt * 16 + col, silu_f(x) * C);
                }
            }
        }
        __syncthreads();
    }
}

// ---------------------------------------------------------------------------
// Masked node kernel (layers 0..2): processes ONLY listed (masked) nodes.
// A-fragments (h_bf + agg) hoisted into registers before the MFMA loop for
// memory-level parallelism (latency-bound regime: ~3 waves/SIMD).
// ---------------------------------------------------------------------------
__global__ __launch_bounds__(256) void node_kernel_masked(
    float* __restrict__ h, bf16_t* __restrict__ h_bf,
    float* __restrict__ agg, const int* __restrict__ list,
    const int* __restrict__ cnt_ptr,
    const bf16_t* __restrict__ w1p, const float* __restrict__ b1,
    const bf16_t* __restrict__ w2p, const float* __restrict__ b2)
{
    __shared__ __align__(16) bf16_t hl[4][16 * 136];
    int t = threadIdx.x, wave = t >> 6, lane = t & 63;
    int quad = lane >> 4, col = lane & 15;
    int cnt = cnt_ptr[0];
    int m0 = blockIdx.x * 64 + wave * 16;
    if (m0 >= cnt) return;  // wave-level exit; no block barriers below
    int lv = list[min(m0 + col, cnt - 1)];  // node id for this col
    int ndc = lv;

    // hoist all 6 A-fragment loads: 4x h_bf + 2x agg (independent requests)
    bf16x8 af[6];
#pragma unroll
    for (int ks = 0; ks < 4; ks++)
        af[ks] = *(const bf16x8*)(h_bf + ndc * HID + ks * 32 + quad * 8);
#pragma unroll
    for (int ks = 4; ks < 6; ks++) {
        const float* ap = agg + ndc * EH + (ks - 4) * 32 + quad * 8;
        floatx4 f0 = *(const floatx4*)ap;
        floatx4 f1 = *(const floatx4*)(ap + 4);
        bf16x8 a;
#pragma unroll
        for (int j = 0; j < 4; j++) { a[j] = (bf16_t)f0[j]; a[j + 4] = (bf16_t)f1[j]; }
        af[ks] = a;
    }
    floatx4 acc[8] = {};
#pragma unroll
    for (int ks = 0; ks < 6; ks++) {
#pragma unroll
        for (int nt = 0; nt < 8; nt++) {
            bf16x8 b = ((const bf16x8*)w1p)[(nt * 6 + ks) * 64 + lane];
            acc[nt] = __builtin_amdgcn_mfma_f32_16x16x32_bf16(af[ks], b, acc[nt], 0, 0, 0);
        }
    }
    if ((m0 + col) < cnt) {
        floatx4 z = {0.0f, 0.0f, 0.0f, 0.0f};
        float* zp = agg + ndc * EH + quad * 8;
        *(floatx4*)zp = z; *(floatx4*)(zp + 4) = z;
        *(floatx4*)(zp + 32) = z; *(floatx4*)(zp + 36) = z;
    }
    bf16_t* myhl = hl[wave];
#pragma unroll
    for (int nt = 0; nt < 8; nt++)
#pragma unroll
        for (int r = 0; r < 4; r++) {
            float x = acc[nt][r] + b1[nt * 16 + col];
            myhl[(quad * 4 + r) * 136 + nt * 16 + col] = (bf16_t)silu_f(x);
        }

    floatx4 acc2[8] = {};
#pragma unroll
    for (int ks = 0; ks < 4; ks++) {
        bf16x8 a = *(const bf16x8*)(myhl + col * 136 + ks * 32 + quad * 8);
#pragma unroll
        for (int nt = 0; nt < 8; nt++) {
            bf16x8 b = ((const bf16x8*)w2p)[(nt * 4 + ks) * 64 + lane];
            acc2[nt] = __builtin_amdgcn_mfma_f32_16x16x32_bf16(a, b, acc2[nt], 0, 0, 0);
        }
    }
#pragma unroll
    for (int r = 0; r < 4; r++) {
        if ((m0 + quad * 4 + r) < cnt) {
            int nd2 = __shfl(lv, quad * 4 + r, 64);
#pragma unroll
            for (int nt = 0; nt < 8; nt++) {
                int n = nt * 16 + col;
                float hv = h[nd2 * HID + n] + acc2[nt][r] + b2[n];
                h[nd2 * HID + n] = hv;
                h_bf[nd2 * HID + n] = (bf16_t)hv;
            }
        }
    }
}

// ---------------------------------------------------------------------------
// Full node kernel (layer 3 + fallback): masked update + fused emb_out.
// ---------------------------------------------------------------------------
__global__ __launch_bounds__(256) void node_kernel(
    float* __restrict__ h, bf16_t* __restrict__ h_bf,
    float* __restrict__ agg, const int* __restrict__ mask,
    const bf16_t* __restrict__ w1p, const float* __restrict__ b1,
    const bf16_t* __restrict__ w2p, const float* __restrict__ b2,
    const bf16_t* __restrict__ wop, const float* __restrict__ bo,
    float* __restrict__ out)
{
    __shared__ __align__(16) bf16_t hl[4][16 * 136];
    int t = threadIdx.x, wave = t >> 6, lane = t & 63;
    int quad = lane >> 4, col = lane & 15;
    int m0 = blockIdx.x * 64 + wave * 16;
    int ndc = min(m0 + col, N_NODES - 1);

    // hoist all 6 A-fragment loads: 4x h_bf + 2x agg
    bf16x8 af[6];
#pragma unroll
    for (int ks = 0; ks < 4; ks++)
        af[ks] = *(const bf16x8*)(h_bf + ndc * HID + ks * 32 + quad * 8);
#pragma unroll
    for (int ks = 4; ks < 6; ks++) {
        const float* ap = agg + ndc * EH + (ks - 4) * 32 + quad * 8;
        floatx4 f0 = *(const floatx4*)ap;
        floatx4 f1 = *(const floatx4*)(ap + 4);
        bf16x8 a;
#pragma unroll
        for (int j = 0; j < 4; j++) { a[j] = (bf16_t)f0[j]; a[j + 4] = (bf16_t)f1[j]; }
        af[ks] = a;
    }
    floatx4 acc[8] = {};
#pragma unroll
    for (int ks = 0; ks < 6; ks++) {
#pragma unroll
        for (int nt = 0; nt < 8; nt++) {
            bf16x8 b = ((const bf16x8*)w1p)[(nt * 6 + ks) * 64 + lane];
            acc[nt] = __builtin_amdgcn_mfma_f32_16x16x32_bf16(af[ks], b, acc[nt], 0, 0, 0);
        }
    }
    bf16_t* myhl = hl[wave];
#pragma unroll
    for (int nt = 0; nt < 8; nt++)
#pragma unroll
        for (int r = 0; r < 4; r++) {
            float x = acc[nt][r] + b1[nt * 16 + col];
            myhl[(quad * 4 + r) * 136 + nt * 16 + col] = (bf16_t)silu_f(x);
        }

    floatx4 acc2[8] = {};
#pragma unroll
    for (int ks = 0; ks < 4; ks++) {
        bf16x8 a = *(const bf16x8*)(myhl + col * 136 + ks * 32 + quad * 8);
#pragma unroll
        for (int nt = 0; nt < 8; nt++) {
            bf16x8 b = ((const bf16x8*)w2p)[(nt * 4 + ks) * 64 + lane];
            acc2[nt] = __builtin_amdgcn_mfma_f32_16x16x32_bf16(a, b, acc2[nt], 0, 0, 0);
        }
    }
#pragma unroll
    for (int r = 0; r < 4; r++) {
        int nd2 = m0 + quad * 4 + r;
        bool valid = nd2 < N_NODES;
        bool upd = valid && mask[min(nd2, N_NODES - 1)] != 0;
        if (upd) {
#pragma unroll
            for (int nt = 0; nt < 8; nt++) {
                int n = nt * 16 + col;
                float hv = h[nd2 * HID + n] + acc2[nt][r] + b2[n];
                h[nd2 * HID + n] = hv;
                bf16_t hb = (bf16_t)hv;
                h_bf[nd2 * HID + n] = hb;
                myhl[(quad * 4 + r) * 136 + n] = hb;
            }
        } else {
#pragma unroll
            for (int nt = 0; nt < 8; nt++) {
                int n = nt * 16 + col;
                myhl[(quad * 4 + r) * 136 + n] =
                    valid ? h_bf[nd2 * HID + n] : (bf16_t)0.0f;
            }
        }
    }
    floatx4 ao[4] = {};
#pragma unroll
    for (int ks = 0; ks < 4; ks++) {
        bf16x8 a = *(const bf16x8*)(myhl + col * 136 + ks * 32 + quad * 8);
#pragma unroll
        for (int nt = 0; nt < 4; nt++) {
            bf16x8 b = ((const bf16x8*)wop)[(nt * 4 + ks) * 64 + lane];
            ao[nt] = __builtin_amdgcn_mfma_f32_16x16x32_bf16(a, b, ao[nt], 0, 0, 0);
        }
    }
#pragma unroll
    for (int r = 0; r < 4; r++) {
        int nd2 = m0 + quad * 4 + r;
        if (nd2 < N_NODES) {
#pragma unroll
            for (int nt = 0; nt < 4; nt++) {
                int n = nt * 16 + col;
                out[nd2 * 64 + n] = ao[nt][r] + bo[n];
            }
        }
    }
}

extern "C" void kernel_launch(void* const* d_in, const int* in_sizes, int n_in,
                              void* d_out, int out_size, void* d_ws, size_t ws_size,
                              hipStream_t stream) {
    const float* h0        = (const float*)d_in[0];
    const int*   edges_a   = (const int*)d_in[1];
    const int*   edges_b   = (const int*)d_in[2];
    const int*   mask_a    = (const int*)d_in[3];
    const int*   mask_b    = (const int*)d_in[4];
    const float* emb_in_w  = (const float*)d_in[5];
    const float* emb_in_b  = (const float*)d_in[6];
    const float* emb_out_w = (const float*)d_in[7];
    const float* emb_out_b = (const float*)d_in[8];
    const float* ew1 = (const float*)d_in[9];
    const float* eb1 = (const float*)d_in[10];
    const float* ew2 = (const float*)d_in[11];
    const float* eb2 = (const float*)d_in[12];
    const float* nw1 = (const float*)d_in[13];
    const float* nb1 = (const float*)d_in[14];
    const float* nw2 = (const float*)d_in[15];
    const float* nb2 = (const float*)d_in[16];

    const size_t SZ_H = 25600000, SZ_HBF = 12800000, SZ_AGG = 12800000;
    const size_t SZ_PK = 655360;
    const size_t SZ_S = 3200000, SZ_BS = 1024, SZ_LIST = 200704;
    const size_t SZ_GBUF = (size_t)2 * 256 * BKT_CAP * 4;  // 8 MB
    const size_t SZ_PROW = 12800000;  // P_row[N][64] fp32
    const size_t SZ_PCOL = 6400000;   // P_col[N][64] bf16

    char* ws = (char*)d_ws;
    size_t off = 0;
    float*  h    = (float*)(ws + off);  off += SZ_H;
    bf16_t* h_bf = (bf16_t*)(ws + off); off += SZ_HBF;
    bf16_t* pk   = (bf16_t*)(ws + off); off += SZ_PK;
    int* ssrc_a = (int*)(ws + off); off += SZ_S;
    int* sdst_a = (int*)(ws + off); off += SZ_S;
    int* ssrc_b = (int*)(ws + off); off += SZ_S;
    int* sdst_b = (int*)(ws + off); off += SZ_S;
    int* gbuf   = (int*)(ws + off); off += SZ_GBUF;
    int* gcur   = (int*)(ws + off); off += 2048;   // gcur|agg contiguous -> one memset
    float* agg  = (float*)(ws + off); off += SZ_AGG;
    int* bases  = (int*)(ws + off); off += 2048;
    int* mcnt_a = (int*)(ws + off); off += 256;
    int* mcnt_b = (int*)(ws + off); off += 256;
    int* ms_a   = (int*)(ws + off); off += SZ_BS;
    int* ms_b   = (int*)(ws + off); off += SZ_BS;
    int* cnt_a  = (int*)(ws + off); off += 256;
    int* cnt_b  = (int*)(ws + off); off += 256;
    int* list_a = (int*)(ws + off); off += SZ_LIST;
    int* list_b = (int*)(ws + off); off += SZ_LIST;
    float*  Prow = (float*)(ws + off);  off += SZ_PROW;
    bf16_t* Pcol = (bf16_t*)(ws + off); off += SZ_PCOL;
    bool ok = (ws_size >= off);  // full fast path

    bf16_t* pk_embin  = pk;
    bf16_t* pk_embout = pk + 8192;
    bf16_t* pk_ew1    = pk + 16384;
    bf16_t* pk_ew2    = pk + 81920;
    bf16_t* pk_nw1    = pk + 98304;
    bf16_t* pk_nw2    = pk + 196608;
    bf16_t* pk_ew1cat = pk + 262144;

    pack_all_kernel<<<160, 256, 0, stream>>>(emb_in_w, emb_out_w, ew1, ew2, nw1, nw2, pk);

    const int node_blocks = (N_NODES + 63) / 64;  // 782
    const int bkt_blocks = (N_EDGES + 2047) / 2048;  // 391
    if (ok) {
        hipMemsetAsync(gcur, 0, 2048 + SZ_AGG, stream);  // cursors + agg in one go
        bucketize_kernel<<<dim3(bkt_blocks, 2), 256, 0, stream>>>(
            edges_a, edges_b, mask_a, mask_b, gcur, gbuf);
        bucket_scan_kernel<<<2, 256, 0, stream>>>(gcur, bases, mcnt_a, mcnt_b);
        bucket_sort_kernel<<<dim3(NCH, 2), 256, 0, stream>>>(
            gcur, gbuf, bases, ssrc_a, sdst_a, ssrc_b, sdst_b);
        // masked-node compaction (lists in ascending node order)
        scan_phase1<<<dim3(NCH, 2), 256, 0, stream>>>(mask_a, mask_b, ms_a, ms_b);
        mask_scan2<<<2, 256, 0, stream>>>(ms_a, ms_b, cnt_a, cnt_b);
        compact_kernel<<<dim3(NCH, 2), 256, 0, stream>>>(mask_a, mask_b, ms_a, ms_b,
                                                         list_a, list_b);
        emb_in_p0_kernel<<<node_blocks, 256, 0, stream>>>(
            h0, pk_embin, emb_in_b, h, h_bf, pk_ew1cat, eb1, Prow, Pcol);
    } else {
        hipMemsetAsync(agg, 0, SZ_AGG, stream);
        emb_in_kernel<<<node_blocks, 256, 0, stream>>>(h0, pk_embin, emb_in_b, h, h_bf);
    }

    for (int l = 0; l < 4; l++) {
        const int* mask = (l & 1) ? mask_b : mask_a;
        float C = (l & 1) ? 0.03125f : 1.0f;
        if (ok) {
            const int* ssrc = (l & 1) ? ssrc_b : ssrc_a;
            const int* sdst = (l & 1) ? sdst_b : sdst_a;
            const int* mp   = (l & 1) ? mcnt_b : mcnt_a;
            if (l > 0)
                pre_edge_kernel<<<node_blocks, 256, 0, stream>>>(
                    h_bf, pk_ew1cat + l * 16384, eb1 + l * 64, Prow, Pcol);
            edge_kernel_pre<<<1024, 256, 0, stream>>>(Prow, Pcol, ssrc, sdst, mp,
                                                      pk_ew2 + l * 4096, eb2 + l * 64,
                                                      agg, C);
        } else {
            const int* edges = (l & 1) ? edges_b : edges_a;
            edge_kernel<<<768, 256, 0, stream>>>(h_bf, edges, mask,
                                                 pk_ew1 + l * 16384, eb1 + l * 64,
                                                 pk_ew2 + l * 4096,  eb2 + l * 64,
                                                 agg, C);
        }
        if (l < 3 && ok) {
            const int* list = (l & 1) ? list_b : list_a;
            const int* cnt  = (l & 1) ? cnt_b : cnt_a;
            node_kernel_masked<<<node_blocks, 256, 0, stream>>>(
                h, h_bf, agg, list, cnt,
                pk_nw1 + l * 24576, nb1 + l * 128,
                pk_nw2 + l * 16384, nb2 + l * 128);
        } else if (l < 3) {
            node_kernel<<<node_blocks, 256, 0, stream>>>(h, h_bf, agg, mask,
                                                         pk_nw1 + l * 24576, nb1 + l * 128,
                                                         pk_nw2 + l * 16384, nb2 + l * 128,
                                                         pk_embout, emb_out_b, (float*)d_out);
            hipMemsetAsync(agg, 0, SZ_AGG, stream);
        } else {
            node_kernel<<<node_blocks, 256, 0, stream>>>(h, h_bf, agg, mask,
                                                         pk_nw1 + 3 * 24576, nb1 + 3 * 128,
                                                         pk_nw2 + 3 * 16384, nb2 + 3 * 128,
                                                         pk_embout, emb_out_b, (float*)d_out);
        }
    }
}